// Round 8
// baseline (1254.665 us; speedup 1.0000x reference)
//
#include <hip/hip_runtime.h>

#define R_ 3
#define T_ 3
#define N_ 50000
#define OPS_ 24
#define E_ 400000
#define B_ 32
#define MAXDEG_ 8
#define QD_ 128
#define ED_ 128
#define H_ 128
#define G4_ (4*H_)   /* 512 */
#define HPAD 168     /* padded LDS h-row (bf16): 128 h + 25 one-hot + pad, 336 B */
#define PSLOTS 64    /* partial row-sum slots per (r,t) */

typedef unsigned short u16;
typedef __attribute__((ext_vector_type(8))) short bf16x8;   // 8 bf16 = 4 VGPRs
typedef __attribute__((ext_vector_type(4))) float f32x4;

#define BF16_ONE ((short)0x3F80)

__device__ __forceinline__ short f2bf(float f){
  union { float f; unsigned u; } v; v.f = f;
  unsigned r = v.u + 0x7fffu + ((v.u >> 16) & 1u);
  return (short)(r >> 16);
}
__device__ __forceinline__ float bf2f(u16 u){
  union { unsigned u; float f; } v; v.u = ((unsigned)u) << 16; return v.f;
}
__device__ __forceinline__ float frcp(float x){ return __builtin_amdgcn_rcpf(x); }
__device__ __forceinline__ float fsig(float x){ return frcp(1.0f + __expf(-x)); }
// tanh(x) = 2*sigmoid(2x) - 1
__device__ __forceinline__ float ftanh(float x){
  return __builtin_fmaf(2.0f, fsig(2.0f * x), -1.0f);
}

// ---------------- query BiLSTM + attention: one block per (r,b) ----------------
__global__ void qattn_kernel(const int* __restrict__ queries, const float* __restrict__ qemb,
    const float* __restrict__ qWih, const float* __restrict__ qWhh,
    const float* __restrict__ qbih, const float* __restrict__ qbhh,
    const float* __restrict__ qlinW, const float* __restrict__ qlinb,
    float* __restrict__ query_attn /* R,T,B,25 */)
{
  int r = blockIdx.x / B_;
  int b = blockIdx.x % B_;
  int tid = threadIdx.x;   // 256
  __shared__ float x[QD_];
  __shared__ float gx[G4_];
  __shared__ float h[H_], c[H_];
  __shared__ float gtmp[G4_];
  __shared__ float hh[2][T_][H_];
  __shared__ float lg[OPS_ + 1];

  int q = queries[b];
  if (tid < QD_) x[tid] = qemb[q * QD_ + tid];
  __syncthreads();

  for (int dir = 0; dir < 2; ++dir){
    const float* Wih = qWih + (size_t)(r * 2 + dir) * G4_ * QD_;
    const float* Whh = qWhh + (size_t)(r * 2 + dir) * G4_ * H_;
    const float* bih = qbih + (r * 2 + dir) * G4_;
    const float* bhh = qbhh + (r * 2 + dir) * G4_;
    for (int j = tid; j < G4_; j += 256){
      const float4* wr = (const float4*)(Wih + (size_t)j * QD_);
      float s = bih[j] + bhh[j];
      for (int k = 0; k < QD_ / 4; ++k){
        float4 wv = wr[k];
        s += wv.x * x[4*k] + wv.y * x[4*k+1] + wv.z * x[4*k+2] + wv.w * x[4*k+3];
      }
      gx[j] = s;
    }
    if (tid < H_){ h[tid] = 0.f; c[tid] = 0.f; }
    __syncthreads();
    for (int t = 0; t < T_; ++t){
      for (int j = tid; j < G4_; j += 256){
        const float4* wr = (const float4*)(Whh + (size_t)j * H_);
        float s = 0.f;
        for (int k = 0; k < H_ / 4; ++k){
          float4 wv = wr[k];
          s += wv.x * h[4*k] + wv.y * h[4*k+1] + wv.z * h[4*k+2] + wv.w * h[4*k+3];
        }
        gtmp[j] = gx[j] + s;
      }
      __syncthreads();
      if (tid < H_){
        float gi = gtmp[tid], gf = gtmp[tid + H_], gg = gtmp[tid + 2*H_], go = gtmp[tid + 3*H_];
        float cn = fsig(gf) * c[tid] + fsig(gi) * ftanh(gg);
        float hn = fsig(go) * ftanh(cn);
        c[tid] = cn; h[tid] = hn;
        hh[dir][t][tid] = hn;
      }
      __syncthreads();
    }
  }

  for (int t = 0; t < T_; ++t){
    if (tid < OPS_ + 1){
      const float* wr = qlinW + tid * (2 * H_);
      float s = qlinb[tid];
      for (int k = 0; k < H_; ++k) s += wr[k] * hh[0][t][k];
      for (int k = 0; k < H_; ++k) s += wr[H_ + k] * hh[1][T_ - 1 - t][k];
      lg[tid] = s;
    }
    __syncthreads();
    if (tid == 0){
      float m = -1e30f;
      for (int o = 0; o < OPS_ + 1; ++o) m = fmaxf(m, lg[o]);
      float sum = 0.f;
      for (int o = 0; o < OPS_ + 1; ++o){ float e = __expf(lg[o] - m); lg[o] = e; sum += e; }
      float inv = frcp(sum);
      for (int o = 0; o < OPS_ + 1; ++o) lg[o] *= inv;
    }
    __syncthreads();
    if (tid < OPS_ + 1) query_attn[((size_t)(r * T_ + t) * B_ + b) * (OPS_ + 1) + tid] = lg[tid];
    __syncthreads();
  }
}

// ------------- entity input projection table: proj[dir][deg(25)][512] -------------
__global__ void eproj_kernel(const float* __restrict__ eemb, const float* __restrict__ eWih,
                             const float* __restrict__ ebih, const float* __restrict__ ebhh,
                             float* __restrict__ proj)
{
  int idx = blockIdx.x * 256 + threadIdx.x;
  if (idx >= 2 * (OPS_ + 1) * G4_) return;
  int j = idx % G4_;
  int v = (idx / G4_) % (OPS_ + 1);
  int dir = idx / (G4_ * (OPS_ + 1));
  const float4* wr = (const float4*)(eWih + (size_t)(dir * G4_ + j) * ED_);
  const float4* er = (const float4*)(eemb + v * ED_);
  float s = ebih[dir * G4_ + j] + ebhh[dir * G4_ + j];
  for (int k = 0; k < ED_ / 4; ++k){
    float4 wv = wr[k], ev = er[k];
    s += wv.x * ev.x + wv.y * ev.y + wv.z * ev.z + wv.w * ev.w;
  }
  proj[idx] = s;
}

// ---- build B-operand buffers in MFMA-fragment order ----
// wtile[dir][gtile(32)][kc(4)][lane(64)][8] bf16 : Whh[j=gtile*16+col][k=kc*32+row*8+jj]
// wonehot[dir][gtile(32)][lane(64)][8] bf16     : k=128+v, v=row*8+jj -> proj[dir][v][j]
__global__ void wbuild_kernel(const float* __restrict__ eWhh, const float* __restrict__ proj,
                              u16* __restrict__ wtile, u16* __restrict__ wonehot)
{
  int idx = blockIdx.x * 256 + threadIdx.x;    // 2*32*5*64*8 = 163840
  if (idx >= 2 * 32 * 5 * 64 * 8) return;
  int jj = idx & 7;
  int lane = (idx >> 3) & 63;
  int kc = (idx >> 9) % 5;
  int gtile = (idx / (8 * 64 * 5)) & 31;
  int dir = idx / (8 * 64 * 5 * 32);
  int row = lane >> 4, col = lane & 15;
  int j = gtile * 16 + col;
  if (kc < 4){
    int k = kc * 32 + row * 8 + jj;
    float v = eWhh[((size_t)dir * G4_ + j) * H_ + k];
    wtile[((((size_t)dir * 32 + gtile) * 4 + kc) * 64 + lane) * 8 + jj] = (u16)f2bf(v);
  } else {
    int vdeg = row * 8 + jj;   // 0..31
    float v = (vdeg <= OPS_) ? proj[(size_t)dir * (OPS_ + 1) * G4_ + (size_t)vdeg * G4_ + j] : 0.f;
    wonehot[(((size_t)dir * 32 + gtile) * 64 + lane) * 8 + jj] = (u16)f2bf(v);
  }
}

// ------ entity BiLSTM (both dirs) + attention softmax, fused: 32 entities/block ------
// B-matrix staged in LDS per dir (tile-ordered, lane-linear ds_read_b128, conflict-
// free). One-hot k-extension (kc4) stays in global: coalesced, tiny. acc zero-init
// -> AGPRs; no launch bound (rounds 4/5/6: any forced VGPR cap spills to scratch).
__global__ __launch_bounds__(256) void elstm_kernel(
    const int* __restrict__ degs,
    const u16* __restrict__ wtile, const u16* __restrict__ wonehot,
    const float* __restrict__ elinW, const float* __restrict__ elinb,
    float* __restrict__ attn /* N,24 */)
{
  int blk = blockIdx.x;
  int tid = threadIdx.x;
  int w = tid >> 6;       // wave 0..3: owns gate cols [w*32, w*32+32) of each gate
  int lane = tid & 63;
  int row = lane >> 4;    // 0..3
  int col = lane & 15;
  int ebase = blk * 32;

  __shared__ __align__(16) short wlds[32 * 4 * 64 * 8];  // 128 KB staged B-tiles
  __shared__ __align__(16) short hl[2][32 * HPAD];       // 21 KB
  __shared__ int dlds[32 * MAXDEG_];                     //  1 KB  (total 150 KB)

  for (int i = tid; i < 2 * 32 * HPAD; i += 256) ((short*)hl)[i] = 0;
  if (tid < 32 * MAXDEG_){
    int e = ebase + (tid >> 3);
    if (e >= N_) e = N_ - 1;
    dlds[tid] = degs[e * MAXDEG_ + (tid & 7)];
  }
  __syncthreads();
  if (tid < 32){
    hl[0][tid * HPAD + H_ + dlds[tid * 8 + 0]] = BF16_ONE;            // dir0 first tt=0
    hl[1][tid * HPAD + H_ + dlds[tid * 8 + MAXDEG_ - 1]] = BF16_ONE;  // dir1 first tt=7
  }
  __syncthreads();

  for (int dir = 0; dir < 2; ++dir){
    // --- stage this dir's B-tiles into LDS (linear 16B copies) ---
    {
      const float4* src = (const float4*)(wtile + (size_t)dir * 32 * 4 * 64 * 8);
      float4* dst = (float4*)wlds;
      for (int i = tid; i < 8192; i += 256) dst[i] = src[i];
    }
    __syncthreads();

    short* hb = hl[dir];
    const u16* Woh = wonehot + (size_t)dir * 32 * 64 * 8;

    float cst[16];
    #pragma unroll
    for (int i = 0; i < 16; ++i) cst[i] = 0.f;

    for (int t = 0; t < MAXDEG_; ++t){
      int tt = dir ? (MAXDEG_ - 1 - t) : t;
      f32x4 acc[16];   // [ct*2 + mt] -> AGPRs
      #pragma unroll
      for (int i = 0; i < 16; ++i) acc[i] = (f32x4){0.f, 0.f, 0.f, 0.f};

      #pragma unroll 1
      for (int kc = 0; kc < 4; ++kc){
        int k0 = kc * 32 + row * 8;
        bf16x8 af[2];
        #pragma unroll
        for (int mt = 0; mt < 2; ++mt)
          af[mt] = *(const bf16x8*)&hb[(mt * 16 + col) * HPAD + k0];
        #pragma unroll
        for (int ct = 0; ct < 8; ++ct){
          int gtile = (ct >> 1) * 8 + 2 * w + (ct & 1);
          bf16x8 bfr = *(const bf16x8*)&wlds[((gtile * 4 + kc) * 64 + lane) * 8];
          #pragma unroll
          for (int mt = 0; mt < 2; ++mt)
            acc[ct * 2 + mt] = __builtin_amdgcn_mfma_f32_16x16x32_bf16(af[mt], bfr, acc[ct * 2 + mt], 0, 0, 0);
        }
      }
      { // kc = 4: one-hot columns (global, coalesced, L2-resident 64 KB)
        int k0 = H_ + row * 8;
        bf16x8 af[2];
        #pragma unroll
        for (int mt = 0; mt < 2; ++mt)
          af[mt] = *(const bf16x8*)&hb[(mt * 16 + col) * HPAD + k0];
        #pragma unroll
        for (int ct = 0; ct < 8; ++ct){
          int gtile = (ct >> 1) * 8 + 2 * w + (ct & 1);
          bf16x8 bfr = *(const bf16x8*)(Woh + (gtile * 64 + lane) * 8);
          #pragma unroll
          for (int mt = 0; mt < 2; ++mt)
            acc[ct * 2 + mt] = __builtin_amdgcn_mfma_f32_16x16x32_bf16(af[mt], bfr, acc[ct * 2 + mt], 0, 0, 0);
        }
      }

      __syncthreads();   // all waves done reading hb

      // --- nonlinearity epilogue: 16 h-units per lane
      #pragma unroll
      for (int mt = 0; mt < 2; ++mt){
        #pragma unroll
        for (int reg = 0; reg < 4; ++reg){
          int m = mt * 16 + row * 4 + reg;
          #pragma unroll
          for (int jj = 0; jj < 2; ++jj){
            int j = w * 32 + jj * 16 + col;
            float gi = acc[(0 + jj) * 2 + mt][reg];
            float gf = acc[(2 + jj) * 2 + mt][reg];
            float gg = acc[(4 + jj) * 2 + mt][reg];
            float go = acc[(6 + jj) * 2 + mt][reg];
            int ci = (mt * 4 + reg) * 2 + jj;
            float cn = fsig(gf) * cst[ci] + fsig(gi) * ftanh(gg);
            float hn = fsig(go) * ftanh(cn);
            cst[ci] = cn;
            hb[m * HPAD + j] = f2bf(hn);
          }
        }
      }
      // --- one-hot maintenance (cols 128..152, disjoint from h writes above)
      if (tid < 32){
        hb[tid * HPAD + H_ + dlds[tid * 8 + tt]] = 0;
        if (t < MAXDEG_ - 1){
          int ttn = dir ? (MAXDEG_ - 2 - t) : (t + 1);
          hb[tid * HPAD + H_ + dlds[tid * 8 + ttn]] = BF16_ONE;
        }
      }
      __syncthreads();   // writes visible before next step's reads
    }
  }

  // ---- attention epilogue: logits + softmax over 24 ops, 8 lanes per entity ----
  int nl = tid >> 3;     // local entity 0..31
  int sub = tid & 7;     // owns ops [sub*3, sub*3+3)
  float lgv[3];
  #pragma unroll
  for (int i = 0; i < 3; ++i) lgv[i] = elinb[sub * 3 + i];
  for (int k = 0; k < 2 * H_; ++k){
    float hv = bf2f((u16)hl[k >> 7][nl * HPAD + (k & 127)]);
    #pragma unroll
    for (int i = 0; i < 3; ++i)
      lgv[i] += hv * elinW[(sub * 3 + i) * 2 * H_ + k];   // 24 KB, L2-resident
  }
  float m = lgv[0];
  #pragma unroll
  for (int i = 1; i < 3; ++i) m = fmaxf(m, lgv[i]);
  m = fmaxf(m, __shfl_xor(m, 1));
  m = fmaxf(m, __shfl_xor(m, 2));
  m = fmaxf(m, __shfl_xor(m, 4));
  float s = 0.f;
  #pragma unroll
  for (int i = 0; i < 3; ++i) s += __expf(lgv[i] - m);
  s += __shfl_xor(s, 1);
  s += __shfl_xor(s, 2);
  s += __shfl_xor(s, 4);
  int n = ebase + nl;
  if (n < N_){
    float inv = frcp(s);
    #pragma unroll
    for (int i = 0; i < 3; ++i)
      attn[(size_t)n * OPS_ + sub * 3 + i] = __expf(lgv[i] - m) * inv;
  }
}

__global__ void wgather_kernel(const float* __restrict__ attn, const int* __restrict__ rels,
                               const int* __restrict__ theads, float* __restrict__ wbuf)
{
  int e = blockIdx.x * 256 + threadIdx.x;
  if (e < E_) wbuf[e] = attn[(size_t)theads[e] * OPS_ + rels[e]];
}

// ------------- propagation: memory layout (N,B) -------------
__global__ void initprop_kernel(const int* __restrict__ heads, const float* __restrict__ qa,
                                float* __restrict__ cur, float* __restrict__ nxt)
{
  int idx = blockIdx.x * 256 + threadIdx.x;
  if (idx < N_ * B_){
    int b = idx & (B_ - 1);
    int n = idx >> 5;
    float v = (heads[b] == n) ? 1.0f : 0.0f;
    cur[idx] = v;
    nxt[idx] = v * qa[b * (OPS_ + 1) + OPS_];
  }
}

// grid-stride edge scatter + fused row-sum partials.
__global__ __launch_bounds__(256) void scatter_kernel(
    const float* __restrict__ min_, float* __restrict__ mout,
    const float* __restrict__ qa,
    const int* __restrict__ rels, const int* __restrict__ theads,
    const int* __restrict__ ttails, const float* __restrict__ wbuf,
    float* __restrict__ partial /* PSLOTS x B */)
{
  __shared__ float qas[B_ * (OPS_ + 1)];
  __shared__ float red[B_];
  int tid = threadIdx.x;
  for (int i = tid; i < B_ * (OPS_ + 1); i += 256) qas[i] = qa[i];
  if (tid < B_) red[tid] = 0.f;
  __syncthreads();
  int b = tid & (B_ - 1);
  int eo = tid >> 5;        // 0..7
  float local = 0.f;
  const int TILES = E_ * B_ / 256;   // 50000
  for (int tile = blockIdx.x; tile < TILES; tile += gridDim.x){
    int e = tile * 8 + eo;
    int rel = rels[e];
    float we = wbuf[e];
    int hh = theads[e], tt = ttails[e];
    float mh = min_[(size_t)hh * B_ + b];
    float mt = min_[(size_t)tt * B_ + b];
    float fwd = qas[b * (OPS_ + 1) + rel] * we * mh;
    float rev = qas[b * (OPS_ + 1) + rel + OPS_ / 2] * we * mt;
    local += fwd + rev;
    if (fwd != 0.f) atomicAdd(&mout[(size_t)tt * B_ + b], fwd);
    if (rev != 0.f) atomicAdd(&mout[(size_t)hh * B_ + b], rev);
  }
  atomicAdd(&red[b], local);
  __syncthreads();
  if (tid < B_) atomicAdd(&partial[(blockIdx.x & (PSLOTS - 1)) * B_ + tid], red[tid]);
}

// normalize a using sums reduced from partials (+ self term qa_cur[b][24]);
// mode 0: also prep next selfadd (nextbuf = v*qa_next[b][24]); mode 1: logacc += v
__global__ void normfuse_kernel(float* __restrict__ a, const float* __restrict__ partial,
                                const float* __restrict__ qa_cur,
                                float* __restrict__ nextbuf, const float* __restrict__ qa_next,
                                float* __restrict__ logacc, int mode)
{
  __shared__ float smem[8][B_];
  __shared__ float sinv[B_];
  int tid = threadIdx.x;
  {
    int b = tid & (B_ - 1), pr = tid >> 5;   // pr 0..7
    float s = 0.f;
    #pragma unroll
    for (int k = 0; k < 8; ++k) s += partial[(pr + 8 * k) * B_ + b];
    smem[pr][b] = s;
  }
  __syncthreads();
  if (tid < B_){
    float s = qa_cur[tid * (OPS_ + 1) + OPS_];
    #pragma unroll
    for (int k = 0; k < 8; ++k) s += smem[k][tid];
    sinv[tid] = frcp(fmaxf(1e-20f, s));
  }
  __syncthreads();
  int idx = blockIdx.x * 256 + tid;
  if (idx < N_ * B_){
    int b = idx & (B_ - 1);
    float v = a[idx] * sinv[b];
    a[idx] = v;
    if (mode == 0) nextbuf[idx] = v * qa_next[b * (OPS_ + 1) + OPS_];
    else logacc[idx] += v;
  }
}

// ------------- final transpose: acc (N,B) -> out (B,N), LDS-tiled -------------
__global__ void transpose_kernel(const float* __restrict__ acc, float* __restrict__ out)
{
  __shared__ float t[B_][72];  // [b][nl], nl<64
  int n0 = blockIdx.x * 64;
  int tid = threadIdx.x;
  for (int i = tid; i < 64 * B_; i += 256){
    int nl = i >> 5, b = i & 31;
    int n = n0 + nl;
    t[b][nl] = (n < N_) ? acc[(size_t)n * B_ + b] : 0.f;
  }
  __syncthreads();
  for (int i = tid; i < 64 * B_; i += 256){
    int b = i >> 6, nl = i & 63;
    int n = n0 + nl;
    if (n < N_) out[(size_t)b * N_ + n] = t[b][nl];
  }
}

extern "C" void kernel_launch(void* const* d_in, const int* in_sizes, int n_in,
                              void* d_out, int out_size, void* d_ws, size_t ws_size,
                              hipStream_t stream)
{
  const int*   queries = (const int*)d_in[0];
  const int*   heads   = (const int*)d_in[1];
  const int*   rels    = (const int*)d_in[2];
  const int*   t_heads = (const int*)d_in[3];
  const int*   t_tails = (const int*)d_in[4];
  const int*   edeg    = (const int*)d_in[5];
  const float* qemb    = (const float*)d_in[6];
  const float* eemb    = (const float*)d_in[7];
  const float* qWih    = (const float*)d_in[8];
  const float* qWhh    = (const float*)d_in[9];
  const float* qbih    = (const float*)d_in[10];
  const float* qbhh    = (const float*)d_in[11];
  const float* eWih    = (const float*)d_in[12];
  const float* eWhh    = (const float*)d_in[13];
  const float* ebih    = (const float*)d_in[14];
  const float* ebhh    = (const float*)d_in[15];
  const float* qlinW   = (const float*)d_in[16];
  const float* qlinb   = (const float*)d_in[17];
  const float* elinW   = (const float*)d_in[18];
  const float* elinb   = (const float*)d_in[19];
  float* out = (float*)d_out;

  char* ws = (char*)d_ws;
  size_t off = 0;
  auto alloc = [&](size_t bytes){ void* p = ws + off; off += (bytes + 255) & ~(size_t)255; return p; };
  float* query_attn = (float*)alloc((size_t)R_ * T_ * B_ * (OPS_ + 1) * 4);  //  29 KB
  float* proj       = (float*)alloc((size_t)2 * (OPS_ + 1) * G4_ * 4);       // 102 KB
  u16*   wtile      = (u16*)  alloc((size_t)2 * 32 * 4 * 64 * 8 * 2);        // 256 KB
  u16*   wonehot    = (u16*)  alloc((size_t)2 * 32 * 64 * 8 * 2);            //  64 KB
  float* attn       = (float*)alloc((size_t)N_ * OPS_ * 4);                  // 4.8 MB
  float* wbuf       = (float*)alloc((size_t)E_ * 4);                         // 1.6 MB
  float* mem0       = (float*)alloc((size_t)N_ * B_ * 4);                    // 6.4 MB
  float* mem1       = (float*)alloc((size_t)N_ * B_ * 4);                    // 6.4 MB
  float* logacc     = (float*)alloc((size_t)N_ * B_ * 4);                    // 6.4 MB
  float* sumsP      = (float*)alloc((size_t)R_ * T_ * PSLOTS * B_ * 4);      // 73 KB
  // total ~26 MB

  hipMemsetAsync(logacc, 0, (size_t)N_ * B_ * 4, stream);
  hipMemsetAsync(sumsP, 0, (size_t)R_ * T_ * PSLOTS * B_ * 4, stream);

  qattn_kernel<<<R_ * B_, 256, 0, stream>>>(queries, qemb, qWih, qWhh, qbih, qbhh,
                                            qlinW, qlinb, query_attn);
  eproj_kernel<<<(2 * (OPS_ + 1) * G4_ + 255) / 256, 256, 0, stream>>>(eemb, eWih, ebih, ebhh, proj);
  wbuild_kernel<<<(2 * 32 * 5 * 64 * 8 + 255) / 256, 256, 0, stream>>>(eWhh, proj, wtile, wonehot);
  elstm_kernel<<<(N_ + 31) / 32, 256, 0, stream>>>(edeg, wtile, wonehot, elinW, elinb, attn);
  wgather_kernel<<<(E_ + 255) / 256, 256, 0, stream>>>(attn, rels, t_heads, wbuf);

  const int NB_BLK = (N_ * B_ + 255) / 256;
  const int SC_BLK = 6250;   // 8 tiles per block
  for (int r = 0; r < R_; ++r){
    const float* qa0 = query_attn + (size_t)(r * T_ + 0) * B_ * (OPS_ + 1);
    initprop_kernel<<<NB_BLK, 256, 0, stream>>>(heads, qa0, mem0, mem1);
    float* cur = mem0;
    float* nxt = mem1;
    for (int t = 0; t < T_; ++t){
      const float* qa = query_attn + (size_t)(r * T_ + t) * B_ * (OPS_ + 1);
      const float* qn = query_attn + (size_t)(r * T_ + t + 1) * B_ * (OPS_ + 1); // used only if t<T_-1
      float* pslot = sumsP + (size_t)(r * T_ + t) * PSLOTS * B_;
      scatter_kernel<<<SC_BLK, 256, 0, stream>>>(cur, nxt, qa, rels, t_heads, t_tails, wbuf, pslot);
      if (t < T_ - 1)
        normfuse_kernel<<<NB_BLK, 256, 0, stream>>>(nxt, pslot, qa, cur, qn, logacc, 0);
      else
        normfuse_kernel<<<NB_BLK, 256, 0, stream>>>(nxt, pslot, qa, cur, qa, logacc, 1);
      float* tmp = cur; cur = nxt; nxt = tmp;
    }
  }
  transpose_kernel<<<(N_ + 63) / 64, 256, 0, stream>>>(logacc, out);
}

// Round 9
// 1223.024 us; speedup vs baseline: 1.0259x; 1.0259x over previous
//
#include <hip/hip_runtime.h>

#define R_ 3
#define T_ 3
#define N_ 50000
#define OPS_ 24
#define E_ 400000
#define B_ 32
#define MAXDEG_ 8
#define QD_ 128
#define ED_ 128
#define H_ 128
#define G4_ (4*H_)   /* 512 */
#define HPAD 168     /* padded LDS h-row (bf16): 128 h + 25 one-hot + pad, 336 B */
#define PSLOTS 64    /* partial row-sum slots per (r,t) */

typedef unsigned short u16;
typedef __attribute__((ext_vector_type(8))) short bf16x8;   // 8 bf16 = 4 VGPRs
typedef __attribute__((ext_vector_type(4))) float f32x4;

#define BF16_ONE ((short)0x3F80)
// intra-wave LDS RAW fence (epilogue writes -> next step's A-frag reads)
#define LDSFENCE() __asm volatile("s_waitcnt lgkmcnt(0)" ::: "memory")

__device__ __forceinline__ short f2bf(float f){
  union { float f; unsigned u; } v; v.f = f;
  unsigned r = v.u + 0x7fffu + ((v.u >> 16) & 1u);
  return (short)(r >> 16);
}
__device__ __forceinline__ float bf2f(u16 u){
  union { unsigned u; float f; } v; v.u = ((unsigned)u) << 16; return v.f;
}
__device__ __forceinline__ float frcp(float x){ return __builtin_amdgcn_rcpf(x); }
__device__ __forceinline__ float fsig(float x){ return frcp(1.0f + __expf(-x)); }
// tanh(x) = 2*sigmoid(2x) - 1
__device__ __forceinline__ float ftanh(float x){
  return __builtin_fmaf(2.0f, fsig(2.0f * x), -1.0f);
}

// ---------------- query BiLSTM + attention: one block per (r,b) ----------------
__global__ void qattn_kernel(const int* __restrict__ queries, const float* __restrict__ qemb,
    const float* __restrict__ qWih, const float* __restrict__ qWhh,
    const float* __restrict__ qbih, const float* __restrict__ qbhh,
    const float* __restrict__ qlinW, const float* __restrict__ qlinb,
    float* __restrict__ query_attn /* R,T,B,25 */)
{
  int r = blockIdx.x / B_;
  int b = blockIdx.x % B_;
  int tid = threadIdx.x;   // 256
  __shared__ float x[QD_];
  __shared__ float gx[G4_];
  __shared__ float h[H_], c[H_];
  __shared__ float gtmp[G4_];
  __shared__ float hh[2][T_][H_];
  __shared__ float lg[OPS_ + 1];

  int q = queries[b];
  if (tid < QD_) x[tid] = qemb[q * QD_ + tid];
  __syncthreads();

  for (int dir = 0; dir < 2; ++dir){
    const float* Wih = qWih + (size_t)(r * 2 + dir) * G4_ * QD_;
    const float* Whh = qWhh + (size_t)(r * 2 + dir) * G4_ * H_;
    const float* bih = qbih + (r * 2 + dir) * G4_;
    const float* bhh = qbhh + (r * 2 + dir) * G4_;
    for (int j = tid; j < G4_; j += 256){
      const float4* wr = (const float4*)(Wih + (size_t)j * QD_);
      float s = bih[j] + bhh[j];
      for (int k = 0; k < QD_ / 4; ++k){
        float4 wv = wr[k];
        s += wv.x * x[4*k] + wv.y * x[4*k+1] + wv.z * x[4*k+2] + wv.w * x[4*k+3];
      }
      gx[j] = s;
    }
    if (tid < H_){ h[tid] = 0.f; c[tid] = 0.f; }
    __syncthreads();
    for (int t = 0; t < T_; ++t){
      for (int j = tid; j < G4_; j += 256){
        const float4* wr = (const float4*)(Whh + (size_t)j * H_);
        float s = 0.f;
        for (int k = 0; k < H_ / 4; ++k){
          float4 wv = wr[k];
          s += wv.x * h[4*k] + wv.y * h[4*k+1] + wv.z * h[4*k+2] + wv.w * h[4*k+3];
        }
        gtmp[j] = gx[j] + s;
      }
      __syncthreads();
      if (tid < H_){
        float gi = gtmp[tid], gf = gtmp[tid + H_], gg = gtmp[tid + 2*H_], go = gtmp[tid + 3*H_];
        float cn = fsig(gf) * c[tid] + fsig(gi) * ftanh(gg);
        float hn = fsig(go) * ftanh(cn);
        c[tid] = cn; h[tid] = hn;
        hh[dir][t][tid] = hn;
      }
      __syncthreads();
    }
  }

  for (int t = 0; t < T_; ++t){
    if (tid < OPS_ + 1){
      const float* wr = qlinW + tid * (2 * H_);
      float s = qlinb[tid];
      for (int k = 0; k < H_; ++k) s += wr[k] * hh[0][t][k];
      for (int k = 0; k < H_; ++k) s += wr[H_ + k] * hh[1][T_ - 1 - t][k];
      lg[tid] = s;
    }
    __syncthreads();
    if (tid == 0){
      float m = -1e30f;
      for (int o = 0; o < OPS_ + 1; ++o) m = fmaxf(m, lg[o]);
      float sum = 0.f;
      for (int o = 0; o < OPS_ + 1; ++o){ float e = __expf(lg[o] - m); lg[o] = e; sum += e; }
      float inv = frcp(sum);
      for (int o = 0; o < OPS_ + 1; ++o) lg[o] *= inv;
    }
    __syncthreads();
    if (tid < OPS_ + 1) query_attn[((size_t)(r * T_ + t) * B_ + b) * (OPS_ + 1) + tid] = lg[tid];
    __syncthreads();
  }
}

// ------------- entity input projection table: proj[dir][deg(25)][512] -------------
__global__ void eproj_kernel(const float* __restrict__ eemb, const float* __restrict__ eWih,
                             const float* __restrict__ ebih, const float* __restrict__ ebhh,
                             float* __restrict__ proj)
{
  int idx = blockIdx.x * 256 + threadIdx.x;
  if (idx >= 2 * (OPS_ + 1) * G4_) return;
  int j = idx % G4_;
  int v = (idx / G4_) % (OPS_ + 1);
  int dir = idx / (G4_ * (OPS_ + 1));
  const float4* wr = (const float4*)(eWih + (size_t)(dir * G4_ + j) * ED_);
  const float4* er = (const float4*)(eemb + v * ED_);
  float s = ebih[dir * G4_ + j] + ebhh[dir * G4_ + j];
  for (int k = 0; k < ED_ / 4; ++k){
    float4 wv = wr[k], ev = er[k];
    s += wv.x * ev.x + wv.y * ev.y + wv.z * ev.z + wv.w * ev.w;
  }
  proj[idx] = s;
}

// ---- build B-operand buffers in MFMA-fragment order ----
// wtile[dir][gtile(32)][kc(4)][lane(64)][8] bf16 : Whh[j=gtile*16+col][k=kc*32+row*8+jj]
// wonehot[dir][gtile(32)][lane(64)][8] bf16     : k=128+v, v=row*8+jj -> proj[dir][v][j]
__global__ void wbuild_kernel(const float* __restrict__ eWhh, const float* __restrict__ proj,
                              u16* __restrict__ wtile, u16* __restrict__ wonehot)
{
  int idx = blockIdx.x * 256 + threadIdx.x;    // 2*32*5*64*8 = 163840
  if (idx >= 2 * 32 * 5 * 64 * 8) return;
  int jj = idx & 7;
  int lane = (idx >> 3) & 63;
  int kc = (idx >> 9) % 5;
  int gtile = (idx / (8 * 64 * 5)) & 31;
  int dir = idx / (8 * 64 * 5 * 32);
  int row = lane >> 4, col = lane & 15;
  int j = gtile * 16 + col;
  if (kc < 4){
    int k = kc * 32 + row * 8 + jj;
    float v = eWhh[((size_t)dir * G4_ + j) * H_ + k];
    wtile[((((size_t)dir * 32 + gtile) * 4 + kc) * 64 + lane) * 8 + jj] = (u16)f2bf(v);
  } else {
    int vdeg = row * 8 + jj;   // 0..31
    float v = (vdeg <= OPS_) ? proj[(size_t)dir * (OPS_ + 1) * G4_ + (size_t)vdeg * G4_ + j] : 0.f;
    wonehot[(((size_t)dir * 32 + gtile) * 64 + lane) * 8 + jj] = (u16)f2bf(v);
  }
}

// ------ entity BiLSTM + attention, BARRIER-FREE K-loop: one wave owns 16 entities ------
// Each wave computes all 512 gates for its 16 entities (acc[32] -> 128 AGPRs), so
// h-state exchange is intra-wave through LDS (lgkmcnt fence, no __syncthreads in the
// step loop). 4 waves/block drift freely and overlap MFMA/VALU/LDS phases. W staged
// in LDS per dir (barriers only at dir boundaries). One-hot K-extension (kc4) B-tiles
// from a 32 KB L1-resident global buffer. (256,1) RAISES the reg cap (LDS already
// limits to 1 block/CU) - avoids both the forced-cap spills (r4-6) and tight packing.
__global__ __launch_bounds__(256, 1) void elstm_kernel(
    const int* __restrict__ degs,
    const u16* __restrict__ wtile, const u16* __restrict__ wonehot,
    const float* __restrict__ elinW, const float* __restrict__ elinb,
    float* __restrict__ attn /* N,24 */)
{
  int tid = threadIdx.x;
  int w = tid >> 6;       // wave 0..3: owns entities [ebase, ebase+16)
  int lane = tid & 63;
  int row = lane >> 4;    // k-quad for A/B frags; op-group for logits
  int col = lane & 15;    // entity (A m-index, logits); gate-col (B n-index)
  int ebase = blockIdx.x * 64 + w * 16;

  __shared__ __align__(16) short wlds[32 * 4 * 64 * 8];  // 128 KB B-tiles (one dir)
  __shared__ __align__(16) short hl[64 * HPAD];          // 21 KB h-rows
  short* hw = hl + (w * 16) * HPAD;                      // this wave's 16 rows

  // per-lane copy of entity(col)'s degree sequence
  int eg = ebase + col; if (eg >= N_) eg = N_ - 1;
  int degr[MAXDEG_];
  #pragma unroll
  for (int dd = 0; dd < MAXDEG_; ++dd) degr[dd] = degs[eg * MAXDEG_ + dd];

  // logits accumulators: entity=col, ops row*6 .. row*6+5
  float lgv[6];
  #pragma unroll
  for (int i = 0; i < 6; ++i) lgv[i] = elinb[row * 6 + i];

  // stage W dir0 into LDS (all waves cooperate)
  {
    const float4* src = (const float4*)wtile;
    float4* dst = (float4*)wlds;
    for (int i = tid; i < 8192; i += 256) dst[i] = src[i];
  }
  __syncthreads();

  for (int dir = 0; dir < 2; ++dir){
    if (dir == 1){
      __syncthreads();   // all waves done reading wlds(dir0)
      const float4* src = (const float4*)(wtile + (size_t)32 * 4 * 64 * 8);
      float4* dst = (float4*)wlds;
      for (int i = tid; i < 8192; i += 256) dst[i] = src[i];
      __syncthreads();
    }
    // zero own h rows + set first one-hot (own-wave only, no barrier)
    {
      float4* hz = (float4*)hw;
      #pragma unroll 1
      for (int i = lane; i < 16 * HPAD * 2 / 16; i += 64) hz[i] = (float4){0.f,0.f,0.f,0.f};
      LDSFENCE();
      if (lane < 16){
        int tt0 = dir ? (MAXDEG_ - 1) : 0;
        hw[lane * HPAD + H_ + degr[tt0]] = BF16_ONE;
      }
      LDSFENCE();
    }

    const u16* Woh = wonehot + (size_t)dir * 32 * 64 * 8;
    float cst[4][8];
    #pragma unroll
    for (int a = 0; a < 4; ++a)
      #pragma unroll
      for (int s = 0; s < 8; ++s) cst[a][s] = 0.f;

    for (int t = 0; t < MAXDEG_; ++t){
      int tt = dir ? (MAXDEG_ - 1 - t) : t;
      f32x4 acc[32];
      #pragma unroll
      for (int g = 0; g < 32; ++g) acc[g] = (f32x4){0.f, 0.f, 0.f, 0.f};

      #pragma unroll 1
      for (int kc = 0; kc < 4; ++kc){
        bf16x8 af = *(const bf16x8*)&hw[col * HPAD + kc * 32 + row * 8];
        #pragma unroll
        for (int g = 0; g < 32; ++g){
          bf16x8 bfr = *(const bf16x8*)&wlds[((g * 4 + kc) * 64 + lane) * 8];
          acc[g] = __builtin_amdgcn_mfma_f32_16x16x32_bf16(af, bfr, acc[g], 0, 0, 0);
        }
      }
      { // kc4: one-hot columns (global, 32 KB, L1-resident)
        bf16x8 af = *(const bf16x8*)&hw[col * HPAD + H_ + row * 8];
        #pragma unroll
        for (int g = 0; g < 32; ++g){
          bf16x8 bfr = *(const bf16x8*)(Woh + ((size_t)g * 64 + lane) * 8);
          acc[g] = __builtin_amdgcn_mfma_f32_16x16x32_bf16(af, bfr, acc[g], 0, 0, 0);
        }
      }

      // epilogue: entity e = row*4+reg (C-layout M), h-unit j = s*16+col (C-layout N)
      #pragma unroll
      for (int reg = 0; reg < 4; ++reg){
        int e = row * 4 + reg;
        #pragma unroll
        for (int s = 0; s < 8; ++s){
          float gi = acc[s][reg];
          float gf = acc[8 + s][reg];
          float gg = acc[16 + s][reg];
          float go = acc[24 + s][reg];
          float cn = fsig(gf) * cst[reg][s] + fsig(gi) * ftanh(gg);
          float hn = fsig(go) * ftanh(cn);
          cst[reg][s] = cn;
          hw[e * HPAD + s * 16 + col] = f2bf(hn);
        }
      }
      // one-hot maintenance (lanes 0..15 own their entity's row; disjoint cols)
      if (lane < 16){
        hw[lane * HPAD + H_ + degr[tt]] = 0;
        if (t < MAXDEG_ - 1){
          int ttn = dir ? (MAXDEG_ - 2 - t) : (t + 1);
          hw[lane * HPAD + H_ + degr[ttn]] = BF16_ONE;
        }
      }
      LDSFENCE();   // drain writes before next step's A-frag reads (intra-wave RAW)
    }

    // accumulate this dir's half of the logits (entity=col, own-wave h)
    #pragma unroll 1
    for (int k = 0; k < H_; ++k){
      float hv = bf2f((u16)hw[col * HPAD + k]);
      #pragma unroll
      for (int i = 0; i < 6; ++i)
        lgv[i] += hv * elinW[(row * 6 + i) * 2 * H_ + dir * H_ + k];
    }
  }

  // softmax over 24 ops: combine the 4 op-groups (lanes col, col+16, col+32, col+48)
  float m = lgv[0];
  #pragma unroll
  for (int i = 1; i < 6; ++i) m = fmaxf(m, lgv[i]);
  m = fmaxf(m, __shfl_xor(m, 16));
  m = fmaxf(m, __shfl_xor(m, 32));
  float s = 0.f;
  #pragma unroll
  for (int i = 0; i < 6; ++i) s += __expf(lgv[i] - m);
  s += __shfl_xor(s, 16);
  s += __shfl_xor(s, 32);
  int n = ebase + col;
  if (n < N_){
    float inv = frcp(s);
    #pragma unroll
    for (int i = 0; i < 6; ++i)
      attn[(size_t)n * OPS_ + row * 6 + i] = __expf(lgv[i] - m) * inv;
  }
}

__global__ void wgather_kernel(const float* __restrict__ attn, const int* __restrict__ rels,
                               const int* __restrict__ theads, float* __restrict__ wbuf)
{
  int e = blockIdx.x * 256 + threadIdx.x;
  if (e < E_) wbuf[e] = attn[(size_t)theads[e] * OPS_ + rels[e]];
}

// ------------- propagation: memory layout (N,B) -------------
__global__ void initprop_kernel(const int* __restrict__ heads, const float* __restrict__ qa,
                                float* __restrict__ cur, float* __restrict__ nxt)
{
  int idx = blockIdx.x * 256 + threadIdx.x;
  if (idx < N_ * B_){
    int b = idx & (B_ - 1);
    int n = idx >> 5;
    float v = (heads[b] == n) ? 1.0f : 0.0f;
    cur[idx] = v;
    nxt[idx] = v * qa[b * (OPS_ + 1) + OPS_];
  }
}

// grid-stride edge scatter + fused row-sum partials.
__global__ __launch_bounds__(256) void scatter_kernel(
    const float* __restrict__ min_, float* __restrict__ mout,
    const float* __restrict__ qa,
    const int* __restrict__ rels, const int* __restrict__ theads,
    const int* __restrict__ ttails, const float* __restrict__ wbuf,
    float* __restrict__ partial /* PSLOTS x B */)
{
  __shared__ float qas[B_ * (OPS_ + 1)];
  __shared__ float red[B_];
  int tid = threadIdx.x;
  for (int i = tid; i < B_ * (OPS_ + 1); i += 256) qas[i] = qa[i];
  if (tid < B_) red[tid] = 0.f;
  __syncthreads();
  int b = tid & (B_ - 1);
  int eo = tid >> 5;        // 0..7
  float local = 0.f;
  const int TILES = E_ * B_ / 256;   // 50000
  for (int tile = blockIdx.x; tile < TILES; tile += gridDim.x){
    int e = tile * 8 + eo;
    int rel = rels[e];
    float we = wbuf[e];
    int hh = theads[e], tt = ttails[e];
    float mh = min_[(size_t)hh * B_ + b];
    float mt = min_[(size_t)tt * B_ + b];
    float fwd = qas[b * (OPS_ + 1) + rel] * we * mh;
    float rev = qas[b * (OPS_ + 1) + rel + OPS_ / 2] * we * mt;
    local += fwd + rev;
    if (fwd != 0.f) atomicAdd(&mout[(size_t)tt * B_ + b], fwd);
    if (rev != 0.f) atomicAdd(&mout[(size_t)hh * B_ + b], rev);
  }
  atomicAdd(&red[b], local);
  __syncthreads();
  if (tid < B_) atomicAdd(&partial[(blockIdx.x & (PSLOTS - 1)) * B_ + tid], red[tid]);
}

// normalize a using sums reduced from partials (+ self term qa_cur[b][24]);
// mode 0: also prep next selfadd (nextbuf = v*qa_next[b][24]); mode 1: logacc += v
__global__ void normfuse_kernel(float* __restrict__ a, const float* __restrict__ partial,
                                const float* __restrict__ qa_cur,
                                float* __restrict__ nextbuf, const float* __restrict__ qa_next,
                                float* __restrict__ logacc, int mode)
{
  __shared__ float smem[8][B_];
  __shared__ float sinv[B_];
  int tid = threadIdx.x;
  {
    int b = tid & (B_ - 1), pr = tid >> 5;   // pr 0..7
    float s = 0.f;
    #pragma unroll
    for (int k = 0; k < 8; ++k) s += partial[(pr + 8 * k) * B_ + b];
    smem[pr][b] = s;
  }
  __syncthreads();
  if (tid < B_){
    float s = qa_cur[tid * (OPS_ + 1) + OPS_];
    #pragma unroll
    for (int k = 0; k < 8; ++k) s += smem[k][tid];
    sinv[tid] = frcp(fmaxf(1e-20f, s));
  }
  __syncthreads();
  int idx = blockIdx.x * 256 + tid;
  if (idx < N_ * B_){
    int b = idx & (B_ - 1);
    float v = a[idx] * sinv[b];
    a[idx] = v;
    if (mode == 0) nextbuf[idx] = v * qa_next[b * (OPS_ + 1) + OPS_];
    else logacc[idx] += v;
  }
}

// ------------- final transpose: acc (N,B) -> out (B,N), LDS-tiled -------------
__global__ void transpose_kernel(const float* __restrict__ acc, float* __restrict__ out)
{
  __shared__ float t[B_][72];  // [b][nl], nl<64
  int n0 = blockIdx.x * 64;
  int tid = threadIdx.x;
  for (int i = tid; i < 64 * B_; i += 256){
    int nl = i >> 5, b = i & 31;
    int n = n0 + nl;
    t[b][nl] = (n < N_) ? acc[(size_t)n * B_ + b] : 0.f;
  }
  __syncthreads();
  for (int i = tid; i < 64 * B_; i += 256){
    int b = i >> 6, nl = i & 63;
    int n = n0 + nl;
    if (n < N_) out[(size_t)b * N_ + n] = t[b][nl];
  }
}

extern "C" void kernel_launch(void* const* d_in, const int* in_sizes, int n_in,
                              void* d_out, int out_size, void* d_ws, size_t ws_size,
                              hipStream_t stream)
{
  const int*   queries = (const int*)d_in[0];
  const int*   heads   = (const int*)d_in[1];
  const int*   rels    = (const int*)d_in[2];
  const int*   t_heads = (const int*)d_in[3];
  const int*   t_tails = (const int*)d_in[4];
  const int*   edeg    = (const int*)d_in[5];
  const float* qemb    = (const float*)d_in[6];
  const float* eemb    = (const float*)d_in[7];
  const float* qWih    = (const float*)d_in[8];
  const float* qWhh    = (const float*)d_in[9];
  const float* qbih    = (const float*)d_in[10];
  const float* qbhh    = (const float*)d_in[11];
  const float* eWih    = (const float*)d_in[12];
  const float* eWhh    = (const float*)d_in[13];
  const float* ebih    = (const float*)d_in[14];
  const float* ebhh    = (const float*)d_in[15];
  const float* qlinW   = (const float*)d_in[16];
  const float* qlinb   = (const float*)d_in[17];
  const float* elinW   = (const float*)d_in[18];
  const float* elinb   = (const float*)d_in[19];
  float* out = (float*)d_out;

  char* ws = (char*)d_ws;
  size_t off = 0;
  auto alloc = [&](size_t bytes){ void* p = ws + off; off += (bytes + 255) & ~(size_t)255; return p; };
  float* query_attn = (float*)alloc((size_t)R_ * T_ * B_ * (OPS_ + 1) * 4);  //  29 KB
  float* proj       = (float*)alloc((size_t)2 * (OPS_ + 1) * G4_ * 4);       // 102 KB
  u16*   wtile      = (u16*)  alloc((size_t)2 * 32 * 4 * 64 * 8 * 2);        // 256 KB
  u16*   wonehot    = (u16*)  alloc((size_t)2 * 32 * 64 * 8 * 2);            //  64 KB
  float* attn       = (float*)alloc((size_t)N_ * OPS_ * 4);                  // 4.8 MB
  float* wbuf       = (float*)alloc((size_t)E_ * 4);                         // 1.6 MB
  float* mem0       = (float*)alloc((size_t)N_ * B_ * 4);                    // 6.4 MB
  float* mem1       = (float*)alloc((size_t)N_ * B_ * 4);                    // 6.4 MB
  float* logacc     = (float*)alloc((size_t)N_ * B_ * 4);                    // 6.4 MB
  float* sumsP      = (float*)alloc((size_t)R_ * T_ * PSLOTS * B_ * 4);      // 73 KB
  // total ~26 MB

  hipMemsetAsync(logacc, 0, (size_t)N_ * B_ * 4, stream);
  hipMemsetAsync(sumsP, 0, (size_t)R_ * T_ * PSLOTS * B_ * 4, stream);

  qattn_kernel<<<R_ * B_, 256, 0, stream>>>(queries, qemb, qWih, qWhh, qbih, qbhh,
                                            qlinW, qlinb, query_attn);
  eproj_kernel<<<(2 * (OPS_ + 1) * G4_ + 255) / 256, 256, 0, stream>>>(eemb, eWih, ebih, ebhh, proj);
  wbuild_kernel<<<(2 * 32 * 5 * 64 * 8 + 255) / 256, 256, 0, stream>>>(eWhh, proj, wtile, wonehot);
  elstm_kernel<<<(N_ + 63) / 64, 256, 0, stream>>>(edeg, wtile, wonehot, elinW, elinb, attn);
  wgather_kernel<<<(E_ + 255) / 256, 256, 0, stream>>>(attn, rels, t_heads, wbuf);

  const int NB_BLK = (N_ * B_ + 255) / 256;
  const int SC_BLK = 6250;   // 8 tiles per block
  for (int r = 0; r < R_; ++r){
    const float* qa0 = query_attn + (size_t)(r * T_ + 0) * B_ * (OPS_ + 1);
    initprop_kernel<<<NB_BLK, 256, 0, stream>>>(heads, qa0, mem0, mem1);
    float* cur = mem0;
    float* nxt = mem1;
    for (int t = 0; t < T_; ++t){
      const float* qa = query_attn + (size_t)(r * T_ + t) * B_ * (OPS_ + 1);
      const float* qn = query_attn + (size_t)(r * T_ + t + 1) * B_ * (OPS_ + 1); // used only if t<T_-1
      float* pslot = sumsP + (size_t)(r * T_ + t) * PSLOTS * B_;
      scatter_kernel<<<SC_BLK, 256, 0, stream>>>(cur, nxt, qa, rels, t_heads, t_tails, wbuf, pslot);
      if (t < T_ - 1)
        normfuse_kernel<<<NB_BLK, 256, 0, stream>>>(nxt, pslot, qa, cur, qn, logacc, 0);
      else
        normfuse_kernel<<<NB_BLK, 256, 0, stream>>>(nxt, pslot, qa, cur, qa, logacc, 1);
      float* tmp = cur; cur = nxt; nxt = tmp;
    }
  }
  transpose_kernel<<<(N_ + 63) / 64, 256, 0, stream>>>(logacc, out);
}

// Round 10
// 987.612 us; speedup vs baseline: 1.2704x; 1.2384x over previous
//
#include <hip/hip_runtime.h>

#define R_ 3
#define T_ 3
#define N_ 50000
#define OPS_ 24
#define E_ 400000
#define B_ 32
#define MAXDEG_ 8
#define QD_ 128
#define ED_ 128
#define H_ 128
#define G4_ (4*H_)   /* 512 */
#define HPAD 168     /* padded LDS h-row (bf16): 128 h + 25 one-hot + pad, 336 B */
#define PSLOTS 64    /* partial row-sum slots per (r,t) */

typedef unsigned short u16;
typedef __attribute__((ext_vector_type(8))) short bf16x8;   // 8 bf16 = 4 VGPRs
typedef __attribute__((ext_vector_type(4))) float f32x4;

#define BF16_ONE ((short)0x3F80)

__device__ __forceinline__ short f2bf(float f){
  union { float f; unsigned u; } v; v.f = f;
  unsigned r = v.u + 0x7fffu + ((v.u >> 16) & 1u);
  return (short)(r >> 16);
}
__device__ __forceinline__ float bf2f(u16 u){
  union { unsigned u; float f; } v; v.u = ((unsigned)u) << 16; return v.f;
}
__device__ __forceinline__ float frcp(float x){ return __builtin_amdgcn_rcpf(x); }
__device__ __forceinline__ float fsig(float x){ return frcp(1.0f + __expf(-x)); }
// tanh(x) = 2*sigmoid(2x) - 1
__device__ __forceinline__ float ftanh(float x){
  return __builtin_fmaf(2.0f, fsig(2.0f * x), -1.0f);
}

// ---------------- query BiLSTM + attention: one block per (r,b) ----------------
__global__ void qattn_kernel(const int* __restrict__ queries, const float* __restrict__ qemb,
    const float* __restrict__ qWih, const float* __restrict__ qWhh,
    const float* __restrict__ qbih, const float* __restrict__ qbhh,
    const float* __restrict__ qlinW, const float* __restrict__ qlinb,
    float* __restrict__ query_attn /* R,T,B,25 */)
{
  int r = blockIdx.x / B_;
  int b = blockIdx.x % B_;
  int tid = threadIdx.x;   // 256
  __shared__ float x[QD_];
  __shared__ float gx[G4_];
  __shared__ float h[H_], c[H_];
  __shared__ float gtmp[G4_];
  __shared__ float hh[2][T_][H_];
  __shared__ float lg[OPS_ + 1];

  int q = queries[b];
  if (tid < QD_) x[tid] = qemb[q * QD_ + tid];
  __syncthreads();

  for (int dir = 0; dir < 2; ++dir){
    const float* Wih = qWih + (size_t)(r * 2 + dir) * G4_ * QD_;
    const float* Whh = qWhh + (size_t)(r * 2 + dir) * G4_ * H_;
    const float* bih = qbih + (r * 2 + dir) * G4_;
    const float* bhh = qbhh + (r * 2 + dir) * G4_;
    for (int j = tid; j < G4_; j += 256){
      const float4* wr = (const float4*)(Wih + (size_t)j * QD_);
      float s = bih[j] + bhh[j];
      for (int k = 0; k < QD_ / 4; ++k){
        float4 wv = wr[k];
        s += wv.x * x[4*k] + wv.y * x[4*k+1] + wv.z * x[4*k+2] + wv.w * x[4*k+3];
      }
      gx[j] = s;
    }
    if (tid < H_){ h[tid] = 0.f; c[tid] = 0.f; }
    __syncthreads();
    for (int t = 0; t < T_; ++t){
      for (int j = tid; j < G4_; j += 256){
        const float4* wr = (const float4*)(Whh + (size_t)j * H_);
        float s = 0.f;
        for (int k = 0; k < H_ / 4; ++k){
          float4 wv = wr[k];
          s += wv.x * h[4*k] + wv.y * h[4*k+1] + wv.z * h[4*k+2] + wv.w * h[4*k+3];
        }
        gtmp[j] = gx[j] + s;
      }
      __syncthreads();
      if (tid < H_){
        float gi = gtmp[tid], gf = gtmp[tid + H_], gg = gtmp[tid + 2*H_], go = gtmp[tid + 3*H_];
        float cn = fsig(gf) * c[tid] + fsig(gi) * ftanh(gg);
        float hn = fsig(go) * ftanh(cn);
        c[tid] = cn; h[tid] = hn;
        hh[dir][t][tid] = hn;
      }
      __syncthreads();
    }
  }

  for (int t = 0; t < T_; ++t){
    if (tid < OPS_ + 1){
      const float* wr = qlinW + tid * (2 * H_);
      float s = qlinb[tid];
      for (int k = 0; k < H_; ++k) s += wr[k] * hh[0][t][k];
      for (int k = 0; k < H_; ++k) s += wr[H_ + k] * hh[1][T_ - 1 - t][k];
      lg[tid] = s;
    }
    __syncthreads();
    if (tid == 0){
      float m = -1e30f;
      for (int o = 0; o < OPS_ + 1; ++o) m = fmaxf(m, lg[o]);
      float sum = 0.f;
      for (int o = 0; o < OPS_ + 1; ++o){ float e = __expf(lg[o] - m); lg[o] = e; sum += e; }
      float inv = frcp(sum);
      for (int o = 0; o < OPS_ + 1; ++o) lg[o] *= inv;
    }
    __syncthreads();
    if (tid < OPS_ + 1) query_attn[((size_t)(r * T_ + t) * B_ + b) * (OPS_ + 1) + tid] = lg[tid];
    __syncthreads();
  }
}

// ------------- entity input projection table: proj[dir][deg(25)][512] -------------
__global__ void eproj_kernel(const float* __restrict__ eemb, const float* __restrict__ eWih,
                             const float* __restrict__ ebih, const float* __restrict__ ebhh,
                             float* __restrict__ proj)
{
  int idx = blockIdx.x * 256 + threadIdx.x;
  if (idx >= 2 * (OPS_ + 1) * G4_) return;
  int j = idx % G4_;
  int v = (idx / G4_) % (OPS_ + 1);
  int dir = idx / (G4_ * (OPS_ + 1));
  const float4* wr = (const float4*)(eWih + (size_t)(dir * G4_ + j) * ED_);
  const float4* er = (const float4*)(eemb + v * ED_);
  float s = ebih[dir * G4_ + j] + ebhh[dir * G4_ + j];
  for (int k = 0; k < ED_ / 4; ++k){
    float4 wv = wr[k], ev = er[k];
    s += wv.x * ev.x + wv.y * ev.y + wv.z * ev.z + wv.w * ev.w;
  }
  proj[idx] = s;
}

// ---- build B-operand buffers in MFMA-fragment order ----
// wtile[dir][gtile(32)][kc(4)][lane(64)][8] bf16 : Whh[j=gtile*16+col][k=kc*32+row*8+jj]
// wonehot[dir][gtile(32)][lane(64)][8] bf16     : k=128+v, v=row*8+jj -> proj[dir][v][j]
__global__ void wbuild_kernel(const float* __restrict__ eWhh, const float* __restrict__ proj,
                              u16* __restrict__ wtile, u16* __restrict__ wonehot)
{
  int idx = blockIdx.x * 256 + threadIdx.x;    // 2*32*5*64*8 = 163840
  if (idx >= 2 * 32 * 5 * 64 * 8) return;
  int jj = idx & 7;
  int lane = (idx >> 3) & 63;
  int kc = (idx >> 9) % 5;
  int gtile = (idx / (8 * 64 * 5)) & 31;
  int dir = idx / (8 * 64 * 5 * 32);
  int row = lane >> 4, col = lane & 15;
  int j = gtile * 16 + col;
  if (kc < 4){
    int k = kc * 32 + row * 8 + jj;
    float v = eWhh[((size_t)dir * G4_ + j) * H_ + k];
    wtile[((((size_t)dir * 32 + gtile) * 4 + kc) * 64 + lane) * 8 + jj] = (u16)f2bf(v);
  } else {
    int vdeg = row * 8 + jj;   // 0..31
    float v = (vdeg <= OPS_) ? proj[(size_t)dir * (OPS_ + 1) * G4_ + (size_t)vdeg * G4_ + j] : 0.f;
    wonehot[(((size_t)dir * 32 + gtile) * 64 + lane) * 8 + jj] = (u16)f2bf(v);
  }
}

// ------ entity BiLSTM: 512 threads, 8 waves, 64 entities; wave-quads cooperate ------
// Quad q (4 waves) owns entities [q*32, q*32+32); within a quad, wave wq owns h-units
// [wq*32, wq*32+32) for ALL FOUR gates (8 gtiles -> acc[16] = 64 AGPRs). 8 waves on
// 4 SIMDs = 2 waves/SIMD resident in the single block the 152.6 KB LDS allows ->
// latency overlap that 1-wave/SIMD rounds (3,7,8,9: all ~550-660 us) never had.
// B staged in LDS (128 KB/dir); one-hot K-extension from 32 KB global (L1/L2).
// h -> houts (global) at each dir's end; attention moved to a separate kernel.
__global__ __launch_bounds__(512) void elstm_kernel(
    const int* __restrict__ degs,
    const u16* __restrict__ wtile, const u16* __restrict__ wonehot,
    u16* __restrict__ houts /* 2,N,128 bf16 */)
{
  int tid = threadIdx.x;
  int lane = tid & 63;
  int w = tid >> 6;        // wave 0..7
  int q = w >> 2;          // quad 0..1
  int wq = w & 3;          // h-slice owner within quad
  int row = lane >> 4, col = lane & 15;
  int ebase = blockIdx.x * 64;

  __shared__ __align__(16) short wlds[32 * 4 * 64 * 8];  // 128 KB
  __shared__ __align__(16) short hl[64 * HPAD];          // 21 KB

  // entity (tid&63)'s degree sequence in registers (for one-hot maintenance)
  int degr[MAXDEG_];
  {
    int eg = ebase + (tid & 63); if (eg >= N_) eg = N_ - 1;
    #pragma unroll
    for (int d = 0; d < MAXDEG_; ++d) degr[d] = degs[eg * MAXDEG_ + d];
  }

  // stage dir0 W + zero h
  {
    const float4* src = (const float4*)wtile;
    float4* dst = (float4*)wlds;
    for (int i = tid; i < 8192; i += 512) dst[i] = src[i];
  }
  for (int i = tid; i < 64 * HPAD; i += 512) hl[i] = 0;
  __syncthreads();
  if (tid < 64) hl[tid * HPAD + H_ + degr[0]] = BF16_ONE;   // dir0 first tt=0
  __syncthreads();

  for (int dir = 0; dir < 2; ++dir){
    const u16* Woh = wonehot + (size_t)dir * 32 * 64 * 8;
    float cst[16];
    #pragma unroll
    for (int i = 0; i < 16; ++i) cst[i] = 0.f;

    for (int t = 0; t < MAXDEG_; ++t){
      int tt = dir ? (MAXDEG_ - 1 - t) : t;
      f32x4 acc[16];   // [ (gate*2+gt2)*2 + mt ]
      #pragma unroll
      for (int i = 0; i < 16; ++i) acc[i] = (f32x4){0.f, 0.f, 0.f, 0.f};

      #pragma unroll 1
      for (int kc = 0; kc < 4; ++kc){
        bf16x8 af0 = *(const bf16x8*)&hl[(q * 32 + col) * HPAD + kc * 32 + row * 8];
        bf16x8 af1 = *(const bf16x8*)&hl[(q * 32 + 16 + col) * HPAD + kc * 32 + row * 8];
        #pragma unroll
        for (int g8 = 0; g8 < 8; ++g8){
          int gtile = (g8 >> 1) * 8 + wq * 2 + (g8 & 1);
          bf16x8 bfr = *(const bf16x8*)&wlds[((gtile * 4 + kc) * 64 + lane) * 8];
          acc[g8 * 2 + 0] = __builtin_amdgcn_mfma_f32_16x16x32_bf16(af0, bfr, acc[g8 * 2 + 0], 0, 0, 0);
          acc[g8 * 2 + 1] = __builtin_amdgcn_mfma_f32_16x16x32_bf16(af1, bfr, acc[g8 * 2 + 1], 0, 0, 0);
        }
      }
      { // kc4: one-hot columns (adds proj[deg] -- input projection)
        bf16x8 af0 = *(const bf16x8*)&hl[(q * 32 + col) * HPAD + H_ + row * 8];
        bf16x8 af1 = *(const bf16x8*)&hl[(q * 32 + 16 + col) * HPAD + H_ + row * 8];
        #pragma unroll
        for (int g8 = 0; g8 < 8; ++g8){
          int gtile = (g8 >> 1) * 8 + wq * 2 + (g8 & 1);
          bf16x8 bfr = *(const bf16x8*)(Woh + ((size_t)gtile * 64 + lane) * 8);
          acc[g8 * 2 + 0] = __builtin_amdgcn_mfma_f32_16x16x32_bf16(af0, bfr, acc[g8 * 2 + 0], 0, 0, 0);
          acc[g8 * 2 + 1] = __builtin_amdgcn_mfma_f32_16x16x32_bf16(af1, bfr, acc[g8 * 2 + 1], 0, 0, 0);
        }
      }

      __syncthreads();   // all h reads done before epilogue writes

      // nonlinearity: 16 h-units per lane (entity e, unit j)
      #pragma unroll
      for (int mt = 0; mt < 2; ++mt){
        #pragma unroll
        for (int reg = 0; reg < 4; ++reg){
          int e = q * 32 + mt * 16 + row * 4 + reg;
          #pragma unroll
          for (int gt2 = 0; gt2 < 2; ++gt2){
            int j = wq * 32 + gt2 * 16 + col;
            float gi = acc[(0 + gt2) * 2 + mt][reg];
            float gf = acc[(2 + gt2) * 2 + mt][reg];
            float gg = acc[(4 + gt2) * 2 + mt][reg];
            float go = acc[(6 + gt2) * 2 + mt][reg];
            int ci = (mt * 4 + reg) * 2 + gt2;
            float cn = fsig(gf) * cst[ci] + fsig(gi) * ftanh(gg);
            float hn = fsig(go) * ftanh(cn);
            cst[ci] = cn;
            hl[e * HPAD + j] = f2bf(hn);
          }
        }
      }
      // one-hot maintenance (cols 128..152, disjoint from h-unit cols 0..127)
      if (tid < 64){
        hl[tid * HPAD + H_ + degr[tt]] = 0;
        if (t < MAXDEG_ - 1){
          int ttn = dir ? (MAXDEG_ - 2 - t) : (t + 1);
          hl[tid * HPAD + H_ + degr[ttn]] = BF16_ONE;
        }
      }
      __syncthreads();   // writes visible before next step's reads
    }

    // save final h for this dir
    for (int i = tid; i < 64 * H_; i += 512){
      int e = i >> 7, k = i & 127;
      int n = ebase + e;
      if (n < N_) houts[(size_t)dir * N_ * H_ + (size_t)n * H_ + k] = (u16)hl[e * HPAD + k];
    }
    if (dir == 0){
      __syncthreads();   // houts copy (reads hl) done before reset
      const float4* src = (const float4*)(wtile + (size_t)32 * 4 * 64 * 8);
      float4* dst = (float4*)wlds;
      for (int i = tid; i < 8192; i += 512) dst[i] = src[i];
      for (int i = tid; i < 64 * HPAD; i += 512) hl[i] = 0;
      __syncthreads();
      if (tid < 64) hl[tid * HPAD + H_ + degr[MAXDEG_ - 1]] = BF16_ONE;  // dir1 first tt=7
      __syncthreads();
    }
  }
}

// ------------- entity attention: 10 entities x 24 ops per block, LDS-staged -------------
__global__ void eattn_kernel(const u16* __restrict__ hf, const u16* __restrict__ hb,
                             const float* __restrict__ elinW, const float* __restrict__ elinb,
                             float* __restrict__ attn /* N,24 */)
{
  __shared__ float W[OPS_][257];
  __shared__ float hhs[10][263];
  __shared__ float lgs[10][OPS_];
  int tid = threadIdx.x;    // 240
  int n0 = blockIdx.x * 10;
  for (int i = tid; i < OPS_ * 256; i += 240) W[i >> 8][i & 255] = elinW[i];
  for (int i = tid; i < 10 * H_; i += 240){
    int nl = i >> 7, k = i & 127;
    int n = n0 + nl;
    if (n < N_){
      hhs[nl][k]        = bf2f(hf[(size_t)n * H_ + k]);
      hhs[nl][H_ + k]   = bf2f(hb[(size_t)n * H_ + k]);
    }
  }
  __syncthreads();
  int nl = tid / OPS_;
  int o  = tid - nl * OPS_;
  int n  = n0 + nl;
  if (n < N_){
    float s = elinb[o];
    #pragma unroll 4
    for (int k = 0; k < 2 * H_; ++k) s += W[o][k] * hhs[nl][k];
    lgs[nl][o] = s;
  }
  __syncthreads();
  if (n < N_){
    float m = -1e30f;
    for (int i = 0; i < OPS_; ++i) m = fmaxf(m, lgs[nl][i]);
    float sum = 0.f;
    for (int i = 0; i < OPS_; ++i) sum += __expf(lgs[nl][i] - m);
    attn[(size_t)n * OPS_ + o] = __expf(lgs[nl][o] - m) * frcp(sum);
  }
}

__global__ void wgather_kernel(const float* __restrict__ attn, const int* __restrict__ rels,
                               const int* __restrict__ theads, float* __restrict__ wbuf)
{
  int e = blockIdx.x * 256 + threadIdx.x;
  if (e < E_) wbuf[e] = attn[(size_t)theads[e] * OPS_ + rels[e]];
}

// ------------- propagation: memory layout (N,B) -------------
__global__ void initprop_kernel(const int* __restrict__ heads, const float* __restrict__ qa,
                                float* __restrict__ cur, float* __restrict__ nxt)
{
  int idx = blockIdx.x * 256 + threadIdx.x;
  if (idx < N_ * B_){
    int b = idx & (B_ - 1);
    int n = idx >> 5;
    float v = (heads[b] == n) ? 1.0f : 0.0f;
    cur[idx] = v;
    nxt[idx] = v * qa[b * (OPS_ + 1) + OPS_];
  }
}

// grid-stride edge scatter + fused row-sum partials.
__global__ __launch_bounds__(256) void scatter_kernel(
    const float* __restrict__ min_, float* __restrict__ mout,
    const float* __restrict__ qa,
    const int* __restrict__ rels, const int* __restrict__ theads,
    const int* __restrict__ ttails, const float* __restrict__ wbuf,
    float* __restrict__ partial /* PSLOTS x B */)
{
  __shared__ float qas[B_ * (OPS_ + 1)];
  __shared__ float red[B_];
  int tid = threadIdx.x;
  for (int i = tid; i < B_ * (OPS_ + 1); i += 256) qas[i] = qa[i];
  if (tid < B_) red[tid] = 0.f;
  __syncthreads();
  int b = tid & (B_ - 1);
  int eo = tid >> 5;        // 0..7
  float local = 0.f;
  const int TILES = E_ * B_ / 256;   // 50000
  for (int tile = blockIdx.x; tile < TILES; tile += gridDim.x){
    int e = tile * 8 + eo;
    int rel = rels[e];
    float we = wbuf[e];
    int hh = theads[e], tt = ttails[e];
    float mh = min_[(size_t)hh * B_ + b];
    float mt = min_[(size_t)tt * B_ + b];
    float fwd = qas[b * (OPS_ + 1) + rel] * we * mh;
    float rev = qas[b * (OPS_ + 1) + rel + OPS_ / 2] * we * mt;
    local += fwd + rev;
    if (fwd != 0.f) atomicAdd(&mout[(size_t)tt * B_ + b], fwd);
    if (rev != 0.f) atomicAdd(&mout[(size_t)hh * B_ + b], rev);
  }
  atomicAdd(&red[b], local);
  __syncthreads();
  if (tid < B_) atomicAdd(&partial[(blockIdx.x & (PSLOTS - 1)) * B_ + tid], red[tid]);
}

// normalize a using sums reduced from partials (+ self term qa_cur[b][24]);
// mode 0: also prep next selfadd (nextbuf = v*qa_next[b][24]); mode 1: logacc += v
__global__ void normfuse_kernel(float* __restrict__ a, const float* __restrict__ partial,
                                const float* __restrict__ qa_cur,
                                float* __restrict__ nextbuf, const float* __restrict__ qa_next,
                                float* __restrict__ logacc, int mode)
{
  __shared__ float smem[8][B_];
  __shared__ float sinv[B_];
  int tid = threadIdx.x;
  {
    int b = tid & (B_ - 1), pr = tid >> 5;   // pr 0..7
    float s = 0.f;
    #pragma unroll
    for (int k = 0; k < 8; ++k) s += partial[(pr + 8 * k) * B_ + b];
    smem[pr][b] = s;
  }
  __syncthreads();
  if (tid < B_){
    float s = qa_cur[tid * (OPS_ + 1) + OPS_];
    #pragma unroll
    for (int k = 0; k < 8; ++k) s += smem[k][tid];
    sinv[tid] = frcp(fmaxf(1e-20f, s));
  }
  __syncthreads();
  int idx = blockIdx.x * 256 + tid;
  if (idx < N_ * B_){
    int b = idx & (B_ - 1);
    float v = a[idx] * sinv[b];
    a[idx] = v;
    if (mode == 0) nextbuf[idx] = v * qa_next[b * (OPS_ + 1) + OPS_];
    else logacc[idx] += v;
  }
}

// ------------- final transpose: acc (N,B) -> out (B,N), LDS-tiled -------------
__global__ void transpose_kernel(const float* __restrict__ acc, float* __restrict__ out)
{
  __shared__ float t[B_][72];  // [b][nl], nl<64
  int n0 = blockIdx.x * 64;
  int tid = threadIdx.x;
  for (int i = tid; i < 64 * B_; i += 256){
    int nl = i >> 5, b = i & 31;
    int n = n0 + nl;
    t[b][nl] = (n < N_) ? acc[(size_t)n * B_ + b] : 0.f;
  }
  __syncthreads();
  for (int i = tid; i < 64 * B_; i += 256){
    int b = i >> 6, nl = i & 63;
    int n = n0 + nl;
    if (n < N_) out[(size_t)b * N_ + n] = t[b][nl];
  }
}

extern "C" void kernel_launch(void* const* d_in, const int* in_sizes, int n_in,
                              void* d_out, int out_size, void* d_ws, size_t ws_size,
                              hipStream_t stream)
{
  const int*   queries = (const int*)d_in[0];
  const int*   heads   = (const int*)d_in[1];
  const int*   rels    = (const int*)d_in[2];
  const int*   t_heads = (const int*)d_in[3];
  const int*   t_tails = (const int*)d_in[4];
  const int*   edeg    = (const int*)d_in[5];
  const float* qemb    = (const float*)d_in[6];
  const float* eemb    = (const float*)d_in[7];
  const float* qWih    = (const float*)d_in[8];
  const float* qWhh    = (const float*)d_in[9];
  const float* qbih    = (const float*)d_in[10];
  const float* qbhh    = (const float*)d_in[11];
  const float* eWih    = (const float*)d_in[12];
  const float* eWhh    = (const float*)d_in[13];
  const float* ebih    = (const float*)d_in[14];
  const float* ebhh    = (const float*)d_in[15];
  const float* qlinW   = (const float*)d_in[16];
  const float* qlinb   = (const float*)d_in[17];
  const float* elinW   = (const float*)d_in[18];
  const float* elinb   = (const float*)d_in[19];
  float* out = (float*)d_out;

  char* ws = (char*)d_ws;
  size_t off = 0;
  auto alloc = [&](size_t bytes){ void* p = ws + off; off += (bytes + 255) & ~(size_t)255; return p; };
  // region: houts (25.6 MB) lives here during [elstm, eattn]; afterwards the same
  // bytes are reused as mem0 / mem1 / logacc (3 x 6.4 MB) for propagation.
  char*  region     = (char*) alloc((size_t)2 * N_ * H_ * 2);                // 25.6 MB
  u16*   houts      = (u16*)region;
  float* mem0       = (float*)region;
  float* mem1       = (float*)(region + (size_t)N_ * B_ * 4);
  float* logacc     = (float*)(region + (size_t)2 * N_ * B_ * 4);
  float* query_attn = (float*)alloc((size_t)R_ * T_ * B_ * (OPS_ + 1) * 4);  //  29 KB
  float* proj       = (float*)alloc((size_t)2 * (OPS_ + 1) * G4_ * 4);       // 102 KB
  u16*   wtile      = (u16*)  alloc((size_t)2 * 32 * 4 * 64 * 8 * 2);        // 256 KB
  u16*   wonehot    = (u16*)  alloc((size_t)2 * 32 * 64 * 8 * 2);            //  64 KB
  float* attn       = (float*)alloc((size_t)N_ * OPS_ * 4);                  // 4.8 MB
  float* wbuf       = (float*)alloc((size_t)E_ * 4);                         // 1.6 MB
  float* sumsP      = (float*)alloc((size_t)R_ * T_ * PSLOTS * B_ * 4);      // 73 KB
  // total ~32.5 MB

  hipMemsetAsync(sumsP, 0, (size_t)R_ * T_ * PSLOTS * B_ * 4, stream);

  qattn_kernel<<<R_ * B_, 256, 0, stream>>>(queries, qemb, qWih, qWhh, qbih, qbhh,
                                            qlinW, qlinb, query_attn);
  eproj_kernel<<<(2 * (OPS_ + 1) * G4_ + 255) / 256, 256, 0, stream>>>(eemb, eWih, ebih, ebhh, proj);
  wbuild_kernel<<<(2 * 32 * 5 * 64 * 8 + 255) / 256, 256, 0, stream>>>(eWhh, proj, wtile, wonehot);
  elstm_kernel<<<(N_ + 63) / 64, 512, 0, stream>>>(edeg, wtile, wonehot, houts);
  eattn_kernel<<<(N_ + 9) / 10, 240, 0, stream>>>(houts, houts + (size_t)N_ * H_,
                                                  elinW, elinb, attn);
  wgather_kernel<<<(E_ + 255) / 256, 256, 0, stream>>>(attn, rels, t_heads, wbuf);

  // houts is dead now; reuse region for propagation buffers
  hipMemsetAsync(logacc, 0, (size_t)N_ * B_ * 4, stream);

  const int NB_BLK = (N_ * B_ + 255) / 256;
  const int SC_BLK = 6250;   // 8 tiles per block
  for (int r = 0; r < R_; ++r){
    const float* qa0 = query_attn + (size_t)(r * T_ + 0) * B_ * (OPS_ + 1);
    initprop_kernel<<<NB_BLK, 256, 0, stream>>>(heads, qa0, mem0, mem1);
    float* cur = mem0;
    float* nxt = mem1;
    for (int t = 0; t < T_; ++t){
      const float* qa = query_attn + (size_t)(r * T_ + t) * B_ * (OPS_ + 1);
      const float* qn = query_attn + (size_t)(r * T_ + t + 1) * B_ * (OPS_ + 1); // used only if t<T_-1
      float* pslot = sumsP + (size_t)(r * T_ + t) * PSLOTS * B_;
      scatter_kernel<<<SC_BLK, 256, 0, stream>>>(cur, nxt, qa, rels, t_heads, t_tails, wbuf, pslot);
      if (t < T_ - 1)
        normfuse_kernel<<<NB_BLK, 256, 0, stream>>>(nxt, pslot, qa, cur, qn, logacc, 0);
      else
        normfuse_kernel<<<NB_BLK, 256, 0, stream>>>(nxt, pslot, qa, cur, qa, logacc, 1);
      float* tmp = cur; cur = nxt; nxt = tmp;
    }
  }
  transpose_kernel<<<(N_ + 63) / 64, 256, 0, stream>>>(logacc, out);
}